// Round 1
// baseline (610.072 us; speedup 1.0000x reference)
//
#include <hip/hip_runtime.h>

#define NN 100000
#define NE 1600000
#define IN_DIM 128
#define HID_DIM 128
#define OUT_DIM 64
#define BN_EPS 1e-5f

// ---------------- degree count ----------------
__global__ __launch_bounds__(256) void k_degrees(const int* __restrict__ src,
                                                 const int* __restrict__ dst,
                                                 int* __restrict__ degO,
                                                 int* __restrict__ degI) {
    int e = blockIdx.x * blockDim.x + threadIdx.x;
    if (e < NE) {
        atomicAdd(&degO[src[e]], 1);
        atomicAdd(&degI[dst[e]], 1);
    }
}

// ---------------- prefix scan (3 kernels) ----------------
// scan1: per-block (1024 elems, 256 thr x 4) inclusive scan + block sums
__global__ __launch_bounds__(256) void k_scan1(const int* __restrict__ deg,
                                               int* __restrict__ incl,
                                               int* __restrict__ bsum, int n) {
    __shared__ int s[256];
    int t = threadIdx.x;
    int base = blockIdx.x * 1024 + t * 4;
    int v0 = (base + 0 < n) ? deg[base + 0] : 0;
    int v1 = (base + 1 < n) ? deg[base + 1] : 0;
    int v2 = (base + 2 < n) ? deg[base + 2] : 0;
    int v3 = (base + 3 < n) ? deg[base + 3] : 0;
    s[t] = v0 + v1 + v2 + v3;
    __syncthreads();
    for (int off = 1; off < 256; off <<= 1) {
        int x = (t >= off) ? s[t - off] : 0;
        __syncthreads();
        s[t] += x;
        __syncthreads();
    }
    int p = (t > 0) ? s[t - 1] : 0;
    if (base + 0 < n) { p += v0; incl[base + 0] = p; }
    if (base + 1 < n) { p += v1; incl[base + 1] = p; }
    if (base + 2 < n) { p += v2; incl[base + 2] = p; }
    if (base + 3 < n) { p += v3; incl[base + 3] = p; }
    if (t == 255) bsum[blockIdx.x] = s[255];
}

// scan2: single block scans block sums (nb <= 128)
__global__ __launch_bounds__(128) void k_scan2(const int* __restrict__ bsum,
                                               int* __restrict__ boff, int nb) {
    __shared__ int s[128];
    int t = threadIdx.x;
    s[t] = (t < nb) ? bsum[t] : 0;
    __syncthreads();
    for (int off = 1; off < 128; off <<= 1) {
        int x = (t >= off) ? s[t - off] : 0;
        __syncthreads();
        s[t] += x;
        __syncthreads();
    }
    boff[t] = (t > 0) ? s[t - 1] : 0;
}

// scan3: row_start (exclusive) = boff[blk] + incl[i] - deg[i]; also cursor copy
__global__ __launch_bounds__(256) void k_scan3(const int* __restrict__ incl,
                                               const int* __restrict__ deg,
                                               const int* __restrict__ boff,
                                               int* __restrict__ rowS,
                                               int* __restrict__ cur, int n) {
    int i = blockIdx.x * blockDim.x + threadIdx.x;
    if (i < n) {
        int rs = boff[i >> 10] + incl[i] - deg[i];
        rowS[i] = rs;
        cur[i] = rs;
        if (i == n - 1) rowS[n] = boff[i >> 10] + incl[i];
    }
}

// ---------------- CSR fill ----------------
__global__ __launch_bounds__(256) void k_fill(const int* __restrict__ src,
                                              const int* __restrict__ dst,
                                              int* __restrict__ cur,
                                              int* __restrict__ col) {
    int e = blockIdx.x * blockDim.x + threadIdx.x;
    if (e < NE) {
        int d = dst[e];
        int pos = atomicAdd(&cur[d], 1);
        col[pos] = src[e];
    }
}

// ---------------- GEMM1: x1 = (h .* rsqrt(degO)) @ W1  [N,128]x[128,128] ----------------
__global__ __launch_bounds__(256) void k_gemm1(const float* __restrict__ h,
                                               const float* __restrict__ W1,
                                               const int* __restrict__ degO,
                                               float* __restrict__ x1) {
    __shared__ float As[64][16];
    __shared__ float Bs[16][128];
    __shared__ float rsA[64];
    int tid = threadIdx.x;
    int row0 = blockIdx.x * 64;
    if (tid < 64) {
        int r = row0 + tid;
        float d = (r < NN) ? (float)degO[r] : 1.f;
        rsA[tid] = rsqrtf(fmaxf(d, 1.f));
    }
    int tx = tid & 31;   // col group (x4) -> 128 cols
    int ty = tid >> 5;   // 8 row groups of 8 rows
    int ar = tid >> 2;           // A load: row in tile 0..63
    int ak = (tid & 3) * 4;      // k offset 0,4,8,12
    int bk = tid >> 4;           // B load: k row 0..15
    int bn = (tid & 15) * 8;     // col 0..120
    float4 acc[8];
#pragma unroll
    for (int r = 0; r < 8; ++r) acc[r] = float4{0.f, 0.f, 0.f, 0.f};
    __syncthreads();
    for (int k0 = 0; k0 < IN_DIM; k0 += 16) {
        float4 av = float4{0.f, 0.f, 0.f, 0.f};
        int grow = row0 + ar;
        if (grow < NN) av = *(const float4*)&h[(size_t)grow * IN_DIM + k0 + ak];
        float rs = rsA[ar];
        As[ar][ak + 0] = av.x * rs;
        As[ar][ak + 1] = av.y * rs;
        As[ar][ak + 2] = av.z * rs;
        As[ar][ak + 3] = av.w * rs;
        float4 bv0 = *(const float4*)&W1[(size_t)(k0 + bk) * HID_DIM + bn];
        float4 bv1 = *(const float4*)&W1[(size_t)(k0 + bk) * HID_DIM + bn + 4];
        *(float4*)&Bs[bk][bn] = bv0;
        *(float4*)&Bs[bk][bn + 4] = bv1;
        __syncthreads();
#pragma unroll
        for (int kk = 0; kk < 16; ++kk) {
            float4 b = *(const float4*)&Bs[kk][tx * 4];
#pragma unroll
            for (int r = 0; r < 8; ++r) {
                float a = As[ty * 8 + r][kk];
                acc[r].x += a * b.x; acc[r].y += a * b.y;
                acc[r].z += a * b.z; acc[r].w += a * b.w;
            }
        }
        __syncthreads();
    }
#pragma unroll
    for (int r = 0; r < 8; ++r) {
        int grow = row0 + ty * 8 + r;
        if (grow < NN) *(float4*)&x1[(size_t)grow * HID_DIM + tx * 4] = acc[r];
    }
}

// ---------------- gather1: y1[i] = (sum_j x1[col[j]]) * rsqrt(degI) + b1 ----------------
__global__ __launch_bounds__(256) void k_gather1(const float* __restrict__ x1,
                                                 const int* __restrict__ rowS,
                                                 const int* __restrict__ col,
                                                 const float* __restrict__ b1,
                                                 float* __restrict__ y1) {
    int node = blockIdx.x * 8 + (threadIdx.x >> 5);
    int f4 = threadIdx.x & 31;   // 32 float4 = 128 feats
    if (node >= NN) return;
    int s0 = rowS[node], s1 = rowS[node + 1];
    const float4* x4 = (const float4*)x1;
    float4 acc = float4{0.f, 0.f, 0.f, 0.f};
    int j = s0;
    for (; j + 3 < s1; j += 4) {
        int a0 = col[j], a1 = col[j + 1], a2 = col[j + 2], a3 = col[j + 3];
        float4 v0 = x4[(size_t)a0 * 32 + f4];
        float4 v1 = x4[(size_t)a1 * 32 + f4];
        float4 v2 = x4[(size_t)a2 * 32 + f4];
        float4 v3 = x4[(size_t)a3 * 32 + f4];
        acc.x += v0.x + v1.x + v2.x + v3.x;
        acc.y += v0.y + v1.y + v2.y + v3.y;
        acc.z += v0.z + v1.z + v2.z + v3.z;
        acc.w += v0.w + v1.w + v2.w + v3.w;
    }
    for (; j < s1; ++j) {
        int a = col[j];
        float4 v = x4[(size_t)a * 32 + f4];
        acc.x += v.x; acc.y += v.y; acc.z += v.z; acc.w += v.w;
    }
    float rs = rsqrtf(fmaxf((float)(s1 - s0), 1.f));
    float4 bb = ((const float4*)b1)[f4];
    float4 o;
    o.x = acc.x * rs + bb.x;
    o.y = acc.y * rs + bb.y;
    o.z = acc.z * rs + bb.z;
    o.w = acc.w * rs + bb.w;
    ((float4*)y1)[(size_t)node * 32 + f4] = o;
}

// ---------------- BN stats: per-channel sum / sumsq ----------------
__global__ __launch_bounds__(256) void k_bnstats(const float* __restrict__ y1,
                                                 float* __restrict__ stats) {
    int f = threadIdx.x & 127;
    int ro = threadIdx.x >> 7;          // 0..1
    int i0 = blockIdx.x * 2 + ro;
    float s = 0.f, ss = 0.f;
    for (int i = i0; i < NN; i += gridDim.x * 2) {
        float v = y1[(size_t)i * HID_DIM + f];
        s += v;
        ss += v * v;
    }
    atomicAdd(&stats[f], s);
    atomicAdd(&stats[128 + f], ss);
}

// ---------------- BN finalize: scale/shift ----------------
__global__ __launch_bounds__(128) void k_bnfinal(float* __restrict__ stats,
                                                 const float* __restrict__ gamma,
                                                 const float* __restrict__ beta) {
    int f = threadIdx.x;
    float mean = stats[f] * (1.f / NN);
    float var = stats[128 + f] * (1.f / NN) - mean * mean;
    var = fmaxf(var, 0.f);
    float sc = gamma[f] * rsqrtf(var + BN_EPS);
    stats[256 + f] = sc;
    stats[384 + f] = beta[f] - mean * sc;
}

// ---------------- GEMM2: x2 = (relu(y1*sc+sh) .* rsqrt(degO)) @ W2  [N,128]x[128,64] ----------------
__global__ __launch_bounds__(256) void k_gemm2(const float* __restrict__ y1,
                                               const float* __restrict__ W2,
                                               const int* __restrict__ degO,
                                               const float* __restrict__ stats,
                                               float* __restrict__ x2) {
    __shared__ float As[64][16];
    __shared__ float Bs[16][64];
    __shared__ float rsA[64];
    __shared__ float sc[128], sh[128];
    int tid = threadIdx.x;
    int row0 = blockIdx.x * 64;
    if (tid < 128) {
        sc[tid] = stats[256 + tid];
        sh[tid] = stats[384 + tid];
    }
    if (tid < 64) {
        int r = row0 + tid;
        float d = (r < NN) ? (float)degO[r] : 1.f;
        rsA[tid] = rsqrtf(fmaxf(d, 1.f));
    }
    int tx = tid & 15;    // col group (x4) -> 64 cols
    int ty = tid >> 4;    // 16 row groups of 4 rows
    int ar = tid >> 2;
    int ak = (tid & 3) * 4;
    int bk = tid >> 4;          // 0..15
    int bn = (tid & 15) * 4;    // 0..60
    float4 acc[4];
#pragma unroll
    for (int r = 0; r < 4; ++r) acc[r] = float4{0.f, 0.f, 0.f, 0.f};
    __syncthreads();
    for (int k0 = 0; k0 < HID_DIM; k0 += 16) {
        float4 av = float4{0.f, 0.f, 0.f, 0.f};
        int grow = row0 + ar;
        if (grow < NN) av = *(const float4*)&y1[(size_t)grow * HID_DIM + k0 + ak];
        float rs = rsA[ar];
        As[ar][ak + 0] = fmaxf(av.x * sc[k0 + ak + 0] + sh[k0 + ak + 0], 0.f) * rs;
        As[ar][ak + 1] = fmaxf(av.y * sc[k0 + ak + 1] + sh[k0 + ak + 1], 0.f) * rs;
        As[ar][ak + 2] = fmaxf(av.z * sc[k0 + ak + 2] + sh[k0 + ak + 2], 0.f) * rs;
        As[ar][ak + 3] = fmaxf(av.w * sc[k0 + ak + 3] + sh[k0 + ak + 3], 0.f) * rs;
        float4 bv = *(const float4*)&W2[(size_t)(k0 + bk) * OUT_DIM + bn];
        *(float4*)&Bs[bk][bn] = bv;
        __syncthreads();
#pragma unroll
        for (int kk = 0; kk < 16; ++kk) {
            float4 b = *(const float4*)&Bs[kk][tx * 4];
#pragma unroll
            for (int r = 0; r < 4; ++r) {
                float a = As[ty * 4 + r][kk];
                acc[r].x += a * b.x; acc[r].y += a * b.y;
                acc[r].z += a * b.z; acc[r].w += a * b.w;
            }
        }
        __syncthreads();
    }
#pragma unroll
    for (int r = 0; r < 4; ++r) {
        int grow = row0 + ty * 4 + r;
        if (grow < NN) *(float4*)&x2[(size_t)grow * OUT_DIM + tx * 4] = acc[r];
    }
}

// ---------------- gather2: out[i] = (sum_j x2[col[j]]) * rsqrt(degI) + b2 ----------------
__global__ __launch_bounds__(256) void k_gather2(const float* __restrict__ x2,
                                                 const int* __restrict__ rowS,
                                                 const int* __restrict__ col,
                                                 const float* __restrict__ b2,
                                                 float* __restrict__ out) {
    int node = blockIdx.x * 16 + (threadIdx.x >> 4);
    int f4 = threadIdx.x & 15;   // 16 float4 = 64 feats
    if (node >= NN) return;
    int s0 = rowS[node], s1 = rowS[node + 1];
    const float4* x4 = (const float4*)x2;
    float4 acc = float4{0.f, 0.f, 0.f, 0.f};
    int j = s0;
    for (; j + 3 < s1; j += 4) {
        int a0 = col[j], a1 = col[j + 1], a2 = col[j + 2], a3 = col[j + 3];
        float4 v0 = x4[(size_t)a0 * 16 + f4];
        float4 v1 = x4[(size_t)a1 * 16 + f4];
        float4 v2 = x4[(size_t)a2 * 16 + f4];
        float4 v3 = x4[(size_t)a3 * 16 + f4];
        acc.x += v0.x + v1.x + v2.x + v3.x;
        acc.y += v0.y + v1.y + v2.y + v3.y;
        acc.z += v0.z + v1.z + v2.z + v3.z;
        acc.w += v0.w + v1.w + v2.w + v3.w;
    }
    for (; j < s1; ++j) {
        int a = col[j];
        float4 v = x4[(size_t)a * 16 + f4];
        acc.x += v.x; acc.y += v.y; acc.z += v.z; acc.w += v.w;
    }
    float rs = rsqrtf(fmaxf((float)(s1 - s0), 1.f));
    float4 bb = ((const float4*)b2)[f4];
    float4 o;
    o.x = acc.x * rs + bb.x;
    o.y = acc.y * rs + bb.y;
    o.z = acc.z * rs + bb.z;
    o.w = acc.w * rs + bb.w;
    ((float4*)out)[(size_t)node * 16 + f4] = o;
}

extern "C" void kernel_launch(void* const* d_in, const int* in_sizes, int n_in,
                              void* d_out, int out_size, void* d_ws, size_t ws_size,
                              hipStream_t stream) {
    const float* h     = (const float*)d_in[0];
    const float* W1    = (const float*)d_in[1];
    const float* b1    = (const float*)d_in[2];
    const float* W2    = (const float*)d_in[3];
    const float* b2    = (const float*)d_in[4];
    const float* gamma = (const float*)d_in[5];
    const float* beta  = (const float*)d_in[6];
    const int*   src   = (const int*)d_in[7];
    const int*   dst   = (const int*)d_in[8];
    float* out = (float*)d_out;

    // workspace layout (element offsets from base)
    int* degO = (int*)d_ws;                 // N
    int* degI = degO + NN;                  // N
    float* stats = (float*)(degO + 2 * NN); // 512 floats (sum,sumsq,scale,shift)
    int* incl = (int*)(stats + 512);        // N
    int* rowS = incl + NN;                  // N+1
    int* cur  = rowS + (NN + 1);            // N
    int* bsum = cur + NN;                   // 128
    int* boff = bsum + 128;                 // 128
    int* col  = boff + 128;                 // E
    size_t colEndEl = (size_t)((int*)col + NE - (int*)d_ws);
    size_t x1Off = (colEndEl + 3) & ~(size_t)3;   // 16B align
    float* x1 = (float*)d_ws + x1Off;       // N*128
    float* y1 = x1 + (size_t)NN * HID_DIM;  // N*128
    float* x2 = x1;                         // reuse (x1 dead after gather1)

    // zero: degO, degI, stats
    hipMemsetAsync(d_ws, 0, (size_t)(2 * NN) * 4 + 512 * 4, stream);

    int egrid = (NE + 255) / 256;
    k_degrees<<<egrid, 256, 0, stream>>>(src, dst, degO, degI);

    int nb = (NN + 1023) / 1024;  // 98
    k_scan1<<<nb, 256, 0, stream>>>(degI, incl, bsum, NN);
    k_scan2<<<1, 128, 0, stream>>>(bsum, boff, nb);
    k_scan3<<<(NN + 255) / 256, 256, 0, stream>>>(incl, degI, boff, rowS, cur, NN);
    k_fill<<<egrid, 256, 0, stream>>>(src, dst, cur, col);

    int ggrid = (NN + 63) / 64;   // 1563
    k_gemm1<<<ggrid, 256, 0, stream>>>(h, W1, degO, x1);
    k_gather1<<<(NN + 7) / 8, 256, 0, stream>>>(x1, rowS, col, b1, y1);
    k_bnstats<<<512, 256, 0, stream>>>(y1, stats);
    k_bnfinal<<<1, 128, 0, stream>>>(stats, gamma, beta);
    k_gemm2<<<ggrid, 256, 0, stream>>>(y1, W2, degO, stats, x2);
    k_gather2<<<(NN + 15) / 16, 256, 0, stream>>>(x2, rowS, col, b2, out);
}

// Round 3
// 477.188 us; speedup vs baseline: 1.2785x; 1.2785x over previous
//
#include <hip/hip_runtime.h>

#define NN 100000
#define NE 1600000
#define BN_EPS 1e-5f

typedef _Float16 f16;
typedef _Float16 f16x4 __attribute__((ext_vector_type(4)));
typedef _Float16 f16x8 __attribute__((ext_vector_type(8)));
typedef float f32x4v __attribute__((ext_vector_type(4)));

// ---------------- degree count ----------------
__global__ __launch_bounds__(256) void k_degrees(const int* __restrict__ src,
                                                 const int* __restrict__ dst,
                                                 int* __restrict__ degO,
                                                 int* __restrict__ degI) {
    int e = blockIdx.x * blockDim.x + threadIdx.x;
    if (e < NE) {
        atomicAdd(&degO[src[e]], 1);
        atomicAdd(&degI[dst[e]], 1);
    }
}

// ---------------- prefix scan (3 kernels) ----------------
__global__ __launch_bounds__(256) void k_scan1(const int* __restrict__ deg,
                                               int* __restrict__ incl,
                                               int* __restrict__ bsum, int n) {
    __shared__ int s[256];
    int t = threadIdx.x;
    int base = blockIdx.x * 1024 + t * 4;
    int v0 = (base + 0 < n) ? deg[base + 0] : 0;
    int v1 = (base + 1 < n) ? deg[base + 1] : 0;
    int v2 = (base + 2 < n) ? deg[base + 2] : 0;
    int v3 = (base + 3 < n) ? deg[base + 3] : 0;
    s[t] = v0 + v1 + v2 + v3;
    __syncthreads();
    for (int off = 1; off < 256; off <<= 1) {
        int x = (t >= off) ? s[t - off] : 0;
        __syncthreads();
        s[t] += x;
        __syncthreads();
    }
    int p = (t > 0) ? s[t - 1] : 0;
    if (base + 0 < n) { p += v0; incl[base + 0] = p; }
    if (base + 1 < n) { p += v1; incl[base + 1] = p; }
    if (base + 2 < n) { p += v2; incl[base + 2] = p; }
    if (base + 3 < n) { p += v3; incl[base + 3] = p; }
    if (t == 255) bsum[blockIdx.x] = s[255];
}

__global__ __launch_bounds__(128) void k_scan2(const int* __restrict__ bsum,
                                               int* __restrict__ boff, int nb) {
    __shared__ int s[128];
    int t = threadIdx.x;
    s[t] = (t < nb) ? bsum[t] : 0;
    __syncthreads();
    for (int off = 1; off < 128; off <<= 1) {
        int x = (t >= off) ? s[t - off] : 0;
        __syncthreads();
        s[t] += x;
        __syncthreads();
    }
    boff[t] = (t > 0) ? s[t - 1] : 0;
}

__global__ __launch_bounds__(256) void k_scan3(const int* __restrict__ incl,
                                               const int* __restrict__ deg,
                                               const int* __restrict__ boff,
                                               int* __restrict__ rowS,
                                               int* __restrict__ cur, int n) {
    int i = blockIdx.x * blockDim.x + threadIdx.x;
    if (i < n) {
        int rs = boff[i >> 10] + incl[i] - deg[i];
        rowS[i] = rs;
        cur[i] = rs;
        if (i == n - 1) rowS[n] = boff[i >> 10] + incl[i];
    }
}

// ---------------- CSR fill ----------------
__global__ __launch_bounds__(256) void k_fill(const int* __restrict__ src,
                                              const int* __restrict__ dst,
                                              int* __restrict__ cur,
                                              int* __restrict__ col) {
    int e = blockIdx.x * blockDim.x + threadIdx.x;
    if (e < NE) {
        int d = dst[e];
        int pos = atomicAdd(&cur[d], 1);
        col[pos] = src[e];
    }
}

// ---------------- weight prep: fp16 transposed [N][K] ----------------
__global__ __launch_bounds__(256) void k_prep(const float* __restrict__ W1,
                                              const float* __restrict__ W2,
                                              f16* __restrict__ W1t,
                                              f16* __restrict__ W2t) {
    int idx = blockIdx.x * 256 + threadIdx.x;
    if (idx < 16384) {
        int n = idx >> 7, k = idx & 127;
        W1t[idx] = (f16)W1[k * 128 + n];
    } else if (idx < 24576) {
        int j = idx - 16384;
        int n = j >> 7, k = j & 127;
        W2t[j] = (f16)W2[k * 64 + n];
    }
}

// ---------------- GEMM1 (MFMA f16): x1h = (h .* rsqrt(degO)) @ W1 ----------------
__global__ __launch_bounds__(256) void k_gemm1(const float* __restrict__ h,
                                               const f16* __restrict__ W1t,
                                               const int* __restrict__ degO,
                                               f16* __restrict__ x1h) {
    __shared__ f16 Ah[128 * 128];
    __shared__ f16 Bt[128 * 128];
    int tid = threadIdx.x;
    int row0 = blockIdx.x * 128;
    // stage B (already [N][K] fp16): 2048 x 16B chunks, XOR swizzle
#pragma unroll
    for (int p = 0; p < 8; ++p) {
        int fi = p * 256 + tid;
        int r = fi >> 4, c = fi & 15;
        uint4 v = *(const uint4*)&W1t[fi * 8];
        *(uint4*)&Bt[r * 128 + ((c ^ (r & 7)) * 8)] = v;
    }
    // stage A: fp32 -> fp16 with degO norm: 4096 float4 chunks
#pragma unroll
    for (int p = 0; p < 16; ++p) {
        int fi = p * 256 + tid;
        int r = fi >> 5, c4 = fi & 31;
        int grow = row0 + r;
        float4 av = float4{0.f, 0.f, 0.f, 0.f};
        float dv = 1.f;
        if (grow < NN) {
            av = *(const float4*)&h[(size_t)grow * 128 + c4 * 4];
            dv = (float)degO[grow];
        }
        float rs = rsqrtf(fmaxf(dv, 1.f));
        f16x4 t;
        t[0] = (f16)(av.x * rs); t[1] = (f16)(av.y * rs);
        t[2] = (f16)(av.z * rs); t[3] = (f16)(av.w * rs);
        int c8 = c4 >> 1, off = (c4 & 1) * 4;
        *(f16x4*)&Ah[r * 128 + ((c8 ^ (r & 7)) * 8) + off] = t;
    }
    __syncthreads();
    int l = tid & 63, w = tid >> 6;
    int lr = l & 15, g = l >> 4;
    int m0 = w * 32;
    f16x8 a[2][4];
#pragma unroll
    for (int m = 0; m < 2; ++m)
#pragma unroll
        for (int kk = 0; kk < 4; ++kk) {
            int row = m0 + m * 16 + lr;
            a[m][kk] = *(f16x8*)&Ah[row * 128 + (((kk * 4 + g) ^ (row & 7)) * 8)];
        }
    f32x4v acc[2][8];
#pragma unroll
    for (int m = 0; m < 2; ++m)
#pragma unroll
        for (int n = 0; n < 8; ++n) acc[m][n] = f32x4v{0.f, 0.f, 0.f, 0.f};
#pragma unroll
    for (int n = 0; n < 8; ++n) {
        int colr = n * 16 + lr;
        f16x8 b[4];
#pragma unroll
        for (int kk = 0; kk < 4; ++kk)
            b[kk] = *(f16x8*)&Bt[colr * 128 + (((kk * 4 + g) ^ (colr & 7)) * 8)];
#pragma unroll
        for (int m = 0; m < 2; ++m)
#pragma unroll
            for (int kk = 0; kk < 4; ++kk)
                acc[m][n] = __builtin_amdgcn_mfma_f32_16x16x32_f16(a[m][kk], b[kk], acc[m][n], 0, 0, 0);
    }
    // barrier: all waves done reading Ah/Bt before epilogue reuses Ah
    __syncthreads();
    // epilogue: scatter C into own Ah rows, then coalesced fp16 store
#pragma unroll
    for (int m = 0; m < 2; ++m)
#pragma unroll
        for (int n = 0; n < 8; ++n)
#pragma unroll
            for (int q = 0; q < 4; ++q) {
                int row = m0 + m * 16 + g * 4 + q;
                Ah[row * 128 + n * 16 + lr] = (f16)acc[m][n][q];
            }
    __syncthreads();
#pragma unroll
    for (int p = 0; p < 8; ++p) {
        int idx = p * 64 + l;
        int r = idx >> 4, c = idx & 15;
        int row = m0 + r, grow = row0 + row;
        uint4 v = *(uint4*)&Ah[row * 128 + c * 8];
        if (grow < NN) *(uint4*)&x1h[(size_t)grow * 128 + c * 8] = v;
    }
}

// ---------------- gather1: y1h = fp16( (sum_j x1h[col[j]]) * rsqrt(degI) + b1 ) ----------------
__global__ __launch_bounds__(256) void k_gather1(const f16* __restrict__ x1h,
                                                 const int* __restrict__ rowS,
                                                 const int* __restrict__ col,
                                                 const float* __restrict__ b1,
                                                 f16* __restrict__ y1h) {
    int node = blockIdx.x * 16 + (threadIdx.x >> 4);
    int f8 = threadIdx.x & 15;   // 16 x 8 halves = 128 feats
    if (node >= NN) return;
    int s0 = rowS[node], s1 = rowS[node + 1];
    const uint4* x4 = (const uint4*)x1h;
    float acc[8] = {0.f, 0.f, 0.f, 0.f, 0.f, 0.f, 0.f, 0.f};
    int j = s0;
    for (; j + 3 < s1; j += 4) {
        int a0 = col[j], a1 = col[j + 1], a2 = col[j + 2], a3 = col[j + 3];
        uint4 v0 = x4[(size_t)a0 * 16 + f8];
        uint4 v1 = x4[(size_t)a1 * 16 + f8];
        uint4 v2 = x4[(size_t)a2 * 16 + f8];
        uint4 v3 = x4[(size_t)a3 * 16 + f8];
        const f16* h0 = (const f16*)&v0; const f16* h1 = (const f16*)&v1;
        const f16* h2 = (const f16*)&v2; const f16* h3 = (const f16*)&v3;
#pragma unroll
        for (int k = 0; k < 8; ++k)
            acc[k] += (float)h0[k] + (float)h1[k] + (float)h2[k] + (float)h3[k];
    }
    for (; j < s1; ++j) {
        int a = col[j];
        uint4 v = x4[(size_t)a * 16 + f8];
        const f16* hp = (const f16*)&v;
#pragma unroll
        for (int k = 0; k < 8; ++k) acc[k] += (float)hp[k];
    }
    float rs = rsqrtf(fmaxf((float)(s1 - s0), 1.f));
    const float4* b4 = (const float4*)b1;
    float4 ba = b4[f8 * 2], bb = b4[f8 * 2 + 1];
    f16x8 o;
    o[0] = (f16)(acc[0] * rs + ba.x); o[1] = (f16)(acc[1] * rs + ba.y);
    o[2] = (f16)(acc[2] * rs + ba.z); o[3] = (f16)(acc[3] * rs + ba.w);
    o[4] = (f16)(acc[4] * rs + bb.x); o[5] = (f16)(acc[5] * rs + bb.y);
    o[6] = (f16)(acc[6] * rs + bb.z); o[7] = (f16)(acc[7] * rs + bb.w);
    *(f16x8*)&y1h[(size_t)node * 128 + f8 * 8] = o;
}

// ---------------- BN stats ----------------
__global__ __launch_bounds__(256) void k_bnstats(const f16* __restrict__ y1h,
                                                 float* __restrict__ stats) {
    int f = threadIdx.x & 127;
    int ro = threadIdx.x >> 7;
    float s = 0.f, ss = 0.f;
    for (int i = blockIdx.x * 2 + ro; i < NN; i += gridDim.x * 2) {
        float v = (float)y1h[(size_t)i * 128 + f];
        s += v;
        ss += v * v;
    }
    atomicAdd(&stats[f], s);
    atomicAdd(&stats[128 + f], ss);
}

__global__ __launch_bounds__(128) void k_bnfinal(float* __restrict__ stats,
                                                 const float* __restrict__ gamma,
                                                 const float* __restrict__ beta) {
    int f = threadIdx.x;
    float mean = stats[f] * (1.f / NN);
    float var = stats[128 + f] * (1.f / NN) - mean * mean;
    var = fmaxf(var, 0.f);
    float sc = gamma[f] * rsqrtf(var + BN_EPS);
    stats[256 + f] = sc;
    stats[384 + f] = beta[f] - mean * sc;
}

// ---------------- GEMM2 (MFMA f16): x2h = (relu(BN(y1)) .* rsqrt(degO)) @ W2 ----------------
__global__ __launch_bounds__(256) void k_gemm2(const f16* __restrict__ y1h,
                                               const f16* __restrict__ W2t,
                                               const int* __restrict__ degO,
                                               const float* __restrict__ stats,
                                               f16* __restrict__ x2h) {
    __shared__ f16 Ah[128 * 128];
    __shared__ f16 Bt[64 * 128];
    __shared__ float sc[128], sh[128];
    int tid = threadIdx.x;
    int row0 = blockIdx.x * 128;
    if (tid < 128) { sc[tid] = stats[256 + tid]; sh[tid] = stats[384 + tid]; }
    // stage B: 1024 chunks
#pragma unroll
    for (int p = 0; p < 4; ++p) {
        int fi = p * 256 + tid;
        int r = fi >> 4, c = fi & 15;
        uint4 v = *(const uint4*)&W2t[fi * 8];
        *(uint4*)&Bt[r * 128 + ((c ^ (r & 7)) * 8)] = v;
    }
    __syncthreads();
    // stage A with BN+ReLU+degO norm: 2048 chunks
#pragma unroll
    for (int p = 0; p < 8; ++p) {
        int fi = p * 256 + tid;
        int r = fi >> 4, c = fi & 15;
        int grow = row0 + r;
        f16x8 t;
        if (grow < NN) {
            uint4 v = *(const uint4*)&y1h[(size_t)grow * 128 + c * 8];
            const f16* hp = (const f16*)&v;
            float rs = rsqrtf(fmaxf((float)degO[grow], 1.f));
#pragma unroll
            for (int i = 0; i < 8; ++i) {
                int ch = c * 8 + i;
                float x = (float)hp[i] * sc[ch] + sh[ch];
                t[i] = (f16)(fmaxf(x, 0.f) * rs);
            }
        } else {
#pragma unroll
            for (int i = 0; i < 8; ++i) t[i] = (f16)0.f;
        }
        *(f16x8*)&Ah[r * 128 + ((c ^ (r & 7)) * 8)] = t;
    }
    __syncthreads();
    int l = tid & 63, w = tid >> 6;
    int lr = l & 15, g = l >> 4;
    int m0 = w * 32;
    f16x8 a[2][4];
#pragma unroll
    for (int m = 0; m < 2; ++m)
#pragma unroll
        for (int kk = 0; kk < 4; ++kk) {
            int row = m0 + m * 16 + lr;
            a[m][kk] = *(f16x8*)&Ah[row * 128 + (((kk * 4 + g) ^ (row & 7)) * 8)];
        }
    f32x4v acc[2][4];
#pragma unroll
    for (int m = 0; m < 2; ++m)
#pragma unroll
        for (int n = 0; n < 4; ++n) acc[m][n] = f32x4v{0.f, 0.f, 0.f, 0.f};
#pragma unroll
    for (int n = 0; n < 4; ++n) {
        int colr = n * 16 + lr;
        f16x8 b[4];
#pragma unroll
        for (int kk = 0; kk < 4; ++kk)
            b[kk] = *(f16x8*)&Bt[colr * 128 + (((kk * 4 + g) ^ (colr & 7)) * 8)];
#pragma unroll
        for (int m = 0; m < 2; ++m)
#pragma unroll
            for (int kk = 0; kk < 4; ++kk)
                acc[m][n] = __builtin_amdgcn_mfma_f32_16x16x32_f16(a[m][kk], b[kk], acc[m][n], 0, 0, 0);
    }
    // barrier: all waves done reading Ah/Bt before epilogue reuses Ah
    __syncthreads();
    // epilogue via LDS (row stride 64)
#pragma unroll
    for (int m = 0; m < 2; ++m)
#pragma unroll
        for (int n = 0; n < 4; ++n)
#pragma unroll
            for (int q = 0; q < 4; ++q) {
                int row = m0 + m * 16 + g * 4 + q;
                Ah[row * 64 + n * 16 + lr] = (f16)acc[m][n][q];
            }
    __syncthreads();
#pragma unroll
    for (int p = 0; p < 4; ++p) {
        int idx = p * 64 + l;
        int r = idx >> 3, c = idx & 7;
        int row = m0 + r, grow = row0 + row;
        uint4 v = *(uint4*)&Ah[row * 64 + c * 8];
        if (grow < NN) *(uint4*)&x2h[(size_t)grow * 64 + c * 8] = v;
    }
}

// ---------------- gather2: out = (sum_j x2h[col[j]]) * rsqrt(degI) + b2 (fp32) ----------------
__global__ __launch_bounds__(256) void k_gather2(const f16* __restrict__ x2h,
                                                 const int* __restrict__ rowS,
                                                 const int* __restrict__ col,
                                                 const float* __restrict__ b2,
                                                 float* __restrict__ out) {
    int node = blockIdx.x * 32 + (threadIdx.x >> 3);
    int f8 = threadIdx.x & 7;   // 8 x 8 halves = 64 feats
    if (node >= NN) return;
    int s0 = rowS[node], s1 = rowS[node + 1];
    const uint4* x4 = (const uint4*)x2h;
    float acc[8] = {0.f, 0.f, 0.f, 0.f, 0.f, 0.f, 0.f, 0.f};
    int j = s0;
    for (; j + 3 < s1; j += 4) {
        int a0 = col[j], a1 = col[j + 1], a2 = col[j + 2], a3 = col[j + 3];
        uint4 v0 = x4[(size_t)a0 * 8 + f8];
        uint4 v1 = x4[(size_t)a1 * 8 + f8];
        uint4 v2 = x4[(size_t)a2 * 8 + f8];
        uint4 v3 = x4[(size_t)a3 * 8 + f8];
        const f16* h0 = (const f16*)&v0; const f16* h1 = (const f16*)&v1;
        const f16* h2 = (const f16*)&v2; const f16* h3 = (const f16*)&v3;
#pragma unroll
        for (int k = 0; k < 8; ++k)
            acc[k] += (float)h0[k] + (float)h1[k] + (float)h2[k] + (float)h3[k];
    }
    for (; j < s1; ++j) {
        int a = col[j];
        uint4 v = x4[(size_t)a * 8 + f8];
        const f16* hp = (const f16*)&v;
#pragma unroll
        for (int k = 0; k < 8; ++k) acc[k] += (float)hp[k];
    }
    float rs = rsqrtf(fmaxf((float)(s1 - s0), 1.f));
    const float4* b4 = (const float4*)b2;
    float4 ba = b4[f8 * 2], bb = b4[f8 * 2 + 1];
    float4 o0, o1;
    o0.x = acc[0] * rs + ba.x; o0.y = acc[1] * rs + ba.y;
    o0.z = acc[2] * rs + ba.z; o0.w = acc[3] * rs + ba.w;
    o1.x = acc[4] * rs + bb.x; o1.y = acc[5] * rs + bb.y;
    o1.z = acc[6] * rs + bb.z; o1.w = acc[7] * rs + bb.w;
    *(float4*)&out[(size_t)node * 64 + f8 * 8] = o0;
    *(float4*)&out[(size_t)node * 64 + f8 * 8 + 4] = o1;
}

extern "C" void kernel_launch(void* const* d_in, const int* in_sizes, int n_in,
                              void* d_out, int out_size, void* d_ws, size_t ws_size,
                              hipStream_t stream) {
    const float* h     = (const float*)d_in[0];
    const float* W1    = (const float*)d_in[1];
    const float* b1    = (const float*)d_in[2];
    const float* W2    = (const float*)d_in[3];
    const float* b2    = (const float*)d_in[4];
    const float* gamma = (const float*)d_in[5];
    const float* beta  = (const float*)d_in[6];
    const int*   src   = (const int*)d_in[7];
    const int*   dst   = (const int*)d_in[8];
    float* out = (float*)d_out;

    // workspace layout (int units)
    int* base = (int*)d_ws;
    int* degO = base;                       // NN
    int* degI = degO + NN;                  // NN
    float* stats = (float*)(degI + NN);     // 512
    int* incl = (int*)(stats + 512);        // NN
    int* rowS = incl + NN;                  // NN+1
    int* cur  = rowS + (NN + 1);            // NN
    int* bsum = cur + NN;                   // 128
    int* boff = bsum + 128;                 // 128
    int* col  = boff + 128;                 // NE
    size_t o = (size_t)(col + NE - base);
    o = (o + 3) & ~(size_t)3;               // 16B align
    f16* W1t = (f16*)(base + o);            // 16384 halves (8192 ints)
    f16* W2t = W1t + 16384;                 // 8192 halves (4096 ints)
    o += 8192 + 4096;
    f16* x1h = (f16*)(base + o);            // NN*128 halves
    o += (size_t)NN * 64;
    f16* y1h = (f16*)(base + o);            // NN*128 halves
    f16* x2h = x1h;                         // reuse

    hipMemsetAsync(d_ws, 0, (size_t)(2 * NN) * 4 + 512 * 4, stream);

    int egrid = (NE + 255) / 256;
    k_degrees<<<egrid, 256, 0, stream>>>(src, dst, degO, degI);

    int nb = (NN + 1023) / 1024;  // 98
    k_scan1<<<nb, 256, 0, stream>>>(degI, incl, bsum, NN);
    k_scan2<<<1, 128, 0, stream>>>(bsum, boff, nb);
    k_scan3<<<(NN + 255) / 256, 256, 0, stream>>>(incl, degI, boff, rowS, cur, NN);
    k_fill<<<egrid, 256, 0, stream>>>(src, dst, cur, col);

    k_prep<<<96, 256, 0, stream>>>(W1, W2, W1t, W2t);

    int ggrid = (NN + 127) / 128;   // 782
    k_gemm1<<<ggrid, 256, 0, stream>>>(h, W1t, degO, x1h);
    k_gather1<<<(NN + 15) / 16, 256, 0, stream>>>(x1h, rowS, col, b1, y1h);
    k_bnstats<<<512, 256, 0, stream>>>(y1h, stats);
    k_bnfinal<<<1, 128, 0, stream>>>(stats, gamma, beta);
    k_gemm2<<<ggrid, 256, 0, stream>>>(y1h, W2t, degO, stats, x2h);
    k_gather2<<<(NN + 31) / 32, 256, 0, stream>>>(x2h, rowS, col, b2, out);
}

// Round 4
// 315.566 us; speedup vs baseline: 1.9333x; 1.5122x over previous
//
#include <hip/hip_runtime.h>

#define NN 100000
#define NE 1600000
#define NB 391          // (NN + 255) >> 8 buckets of 256 nodes
#define EPB 8192        // edges per block in bucket passes
#define BN_EPS 1e-5f

typedef _Float16 f16;
typedef _Float16 f16x4 __attribute__((ext_vector_type(4)));
typedef _Float16 f16x8 __attribute__((ext_vector_type(8)));
typedef float f32x4v __attribute__((ext_vector_type(4)));

// ---------------- kA: global bucket histograms (dst>>8 and src>>8) ----------------
__global__ __launch_bounds__(256) void kA(const int* __restrict__ src,
                                          const int* __restrict__ dst,
                                          int* __restrict__ cntD,
                                          int* __restrict__ cntS) {
    __shared__ int hD[NB], hS[NB];
    for (int i = threadIdx.x; i < NB; i += 256) { hD[i] = 0; hS[i] = 0; }
    __syncthreads();
    int e0 = blockIdx.x * EPB;
    int e1 = min(e0 + EPB, NE);
    for (int e = e0 + threadIdx.x; e < e1; e += 256) {
        atomicAdd(&hD[dst[e] >> 8], 1);
        atomicAdd(&hS[src[e] >> 8], 1);
    }
    __syncthreads();
    for (int i = threadIdx.x; i < NB; i += 256) {
        if (hD[i]) atomicAdd(&cntD[i], hD[i]);
        if (hS[i]) atomicAdd(&cntS[i], hS[i]);
    }
}

// ---------------- kB: scan bucket histograms -> bases + cursors ----------------
__global__ __launch_bounds__(512) void kB(const int* __restrict__ cntD,
                                          const int* __restrict__ cntS,
                                          int* __restrict__ baseD,
                                          int* __restrict__ baseS,
                                          int* __restrict__ curD,
                                          int* __restrict__ curS,
                                          int* __restrict__ rowS) {
    __shared__ int sD[512], sS[512];
    int t = threadIdx.x;
    int vD = (t < NB) ? cntD[t] : 0;
    int vS = (t < NB) ? cntS[t] : 0;
    sD[t] = vD; sS[t] = vS;
    __syncthreads();
    for (int off = 1; off < 512; off <<= 1) {
        int xD = (t >= off) ? sD[t - off] : 0;
        int xS = (t >= off) ? sS[t - off] : 0;
        __syncthreads();
        sD[t] += xD; sS[t] += xS;
        __syncthreads();
    }
    if (t < NB) {
        int bD = sD[t] - vD, bS = sS[t] - vS;
        baseD[t] = bD; baseS[t] = bS;
        curD[t] = bD; curS[t] = bS;
    }
    if (t == 0) { baseD[NB] = NE; baseS[NB] = NE; rowS[NN] = NE; }
}

// ---------------- kC: bucketed scatter of edges ----------------
__global__ __launch_bounds__(256) void kC(const int* __restrict__ src,
                                          const int* __restrict__ dst,
                                          int* __restrict__ curD,
                                          int* __restrict__ curS,
                                          uint2* __restrict__ pairs,
                                          int* __restrict__ srcBuck) {
    __shared__ int hD[NB], hS[NB], bD_[NB], bS_[NB];
    for (int i = threadIdx.x; i < NB; i += 256) { hD[i] = 0; hS[i] = 0; }
    __syncthreads();
    int e0 = blockIdx.x * EPB;
    int e1 = min(e0 + EPB, NE);
    // round 1: count
    for (int e = e0 + threadIdx.x; e < e1; e += 256) {
        atomicAdd(&hD[dst[e] >> 8], 1);
        atomicAdd(&hS[src[e] >> 8], 1);
    }
    __syncthreads();
    // reserve global ranges, reset local cursors
    for (int i = threadIdx.x; i < NB; i += 256) {
        bD_[i] = hD[i] ? atomicAdd(&curD[i], hD[i]) : 0;
        bS_[i] = hS[i] ? atomicAdd(&curS[i], hS[i]) : 0;
        hD[i] = 0; hS[i] = 0;
    }
    __syncthreads();
    // round 2: place
    for (int e = e0 + threadIdx.x; e < e1; e += 256) {
        int d = dst[e], s = src[e];
        int rD = atomicAdd(&hD[d >> 8], 1);
        pairs[bD_[d >> 8] + rD] = uint2{(unsigned)d, (unsigned)s};
        int rS = atomicAdd(&hS[s >> 8], 1);
        srcBuck[bS_[s >> 8] + rS] = s;
    }
}

// ---------------- kD: per-bucket fine CSR (rowS + col) ----------------
__global__ __launch_bounds__(256) void kD(const uint2* __restrict__ pairs,
                                          const int* __restrict__ baseD,
                                          int* __restrict__ rowS,
                                          int* __restrict__ col) {
    __shared__ int cnt[256], s[256];
    int b = blockIdx.x, t = threadIdx.x;
    int p0 = baseD[b], p1 = baseD[b + 1];
    cnt[t] = 0;
    __syncthreads();
    for (int p = p0 + t; p < p1; p += 256)
        atomicAdd(&cnt[pairs[p].x & 255], 1);
    __syncthreads();
    int v = cnt[t];
    s[t] = v;
    __syncthreads();
    for (int off = 1; off < 256; off <<= 1) {
        int x = (t >= off) ? s[t - off] : 0;
        __syncthreads();
        s[t] += x;
        __syncthreads();
    }
    int excl = s[t] - v;
    int node = b * 256 + t;
    if (node < NN) rowS[node] = p0 + excl;
    cnt[t] = excl;   // reuse as scatter cursor
    __syncthreads();
    for (int p = p0 + t; p < p1; p += 256) {
        uint2 e = pairs[p];
        int r = atomicAdd(&cnt[e.x & 255], 1);
        col[p0 + r] = (int)e.y;
    }
}

// ---------------- kE: per-bucket out-degree ----------------
__global__ __launch_bounds__(256) void kE(const int* __restrict__ srcBuck,
                                          const int* __restrict__ baseS,
                                          int* __restrict__ degO) {
    __shared__ int cnt[256];
    int b = blockIdx.x, t = threadIdx.x;
    cnt[t] = 0;
    __syncthreads();
    int p0 = baseS[b], p1 = baseS[b + 1];
    for (int p = p0 + t; p < p1; p += 256)
        atomicAdd(&cnt[srcBuck[p] & 255], 1);
    __syncthreads();
    int node = b * 256 + t;
    if (node < NN) degO[node] = cnt[t];
}

// ---------------- weight prep: fp16 transposed [N][K] ----------------
__global__ __launch_bounds__(256) void k_prep(const float* __restrict__ W1,
                                              const float* __restrict__ W2,
                                              f16* __restrict__ W1t,
                                              f16* __restrict__ W2t) {
    int idx = blockIdx.x * 256 + threadIdx.x;
    if (idx < 16384) {
        int n = idx >> 7, k = idx & 127;
        W1t[idx] = (f16)W1[k * 128 + n];
    } else if (idx < 24576) {
        int j = idx - 16384;
        int n = j >> 7, k = j & 127;
        W2t[j] = (f16)W2[k * 64 + n];
    }
}

// ---------------- GEMM1 (MFMA f16): x1h = (h .* rsqrt(degO)) @ W1 ----------------
__global__ __launch_bounds__(256) void k_gemm1(const float* __restrict__ h,
                                               const f16* __restrict__ W1t,
                                               const int* __restrict__ degO,
                                               f16* __restrict__ x1h) {
    __shared__ f16 Ah[128 * 128];
    __shared__ f16 Bt[128 * 128];
    int tid = threadIdx.x;
    int row0 = blockIdx.x * 128;
#pragma unroll
    for (int p = 0; p < 8; ++p) {
        int fi = p * 256 + tid;
        int r = fi >> 4, c = fi & 15;
        uint4 v = *(const uint4*)&W1t[fi * 8];
        *(uint4*)&Bt[r * 128 + ((c ^ (r & 7)) * 8)] = v;
    }
#pragma unroll
    for (int p = 0; p < 16; ++p) {
        int fi = p * 256 + tid;
        int r = fi >> 5, c4 = fi & 31;
        int grow = row0 + r;
        float4 av = float4{0.f, 0.f, 0.f, 0.f};
        float dv = 1.f;
        if (grow < NN) {
            av = *(const float4*)&h[(size_t)grow * 128 + c4 * 4];
            dv = (float)degO[grow];
        }
        float rs = rsqrtf(fmaxf(dv, 1.f));
        f16x4 t;
        t[0] = (f16)(av.x * rs); t[1] = (f16)(av.y * rs);
        t[2] = (f16)(av.z * rs); t[3] = (f16)(av.w * rs);
        int c8 = c4 >> 1, off = (c4 & 1) * 4;
        *(f16x4*)&Ah[r * 128 + ((c8 ^ (r & 7)) * 8) + off] = t;
    }
    __syncthreads();
    int l = tid & 63, w = tid >> 6;
    int lr = l & 15, g = l >> 4;
    int m0 = w * 32;
    f16x8 a[2][4];
#pragma unroll
    for (int m = 0; m < 2; ++m)
#pragma unroll
        for (int kk = 0; kk < 4; ++kk) {
            int row = m0 + m * 16 + lr;
            a[m][kk] = *(f16x8*)&Ah[row * 128 + (((kk * 4 + g) ^ (row & 7)) * 8)];
        }
    f32x4v acc[2][8];
#pragma unroll
    for (int m = 0; m < 2; ++m)
#pragma unroll
        for (int n = 0; n < 8; ++n) acc[m][n] = f32x4v{0.f, 0.f, 0.f, 0.f};
#pragma unroll
    for (int n = 0; n < 8; ++n) {
        int colr = n * 16 + lr;
        f16x8 b[4];
#pragma unroll
        for (int kk = 0; kk < 4; ++kk)
            b[kk] = *(f16x8*)&Bt[colr * 128 + (((kk * 4 + g) ^ (colr & 7)) * 8)];
#pragma unroll
        for (int m = 0; m < 2; ++m)
#pragma unroll
            for (int kk = 0; kk < 4; ++kk)
                acc[m][n] = __builtin_amdgcn_mfma_f32_16x16x32_f16(a[m][kk], b[kk], acc[m][n], 0, 0, 0);
    }
    __syncthreads();
#pragma unroll
    for (int m = 0; m < 2; ++m)
#pragma unroll
        for (int n = 0; n < 8; ++n)
#pragma unroll
            for (int q = 0; q < 4; ++q) {
                int row = m0 + m * 16 + g * 4 + q;
                Ah[row * 128 + n * 16 + lr] = (f16)acc[m][n][q];
            }
    __syncthreads();
#pragma unroll
    for (int p = 0; p < 8; ++p) {
        int idx = p * 64 + l;
        int r = idx >> 4, c = idx & 15;
        int row = m0 + r, grow = row0 + row;
        uint4 v = *(uint4*)&Ah[row * 128 + c * 8];
        if (grow < NN) *(uint4*)&x1h[(size_t)grow * 128 + c * 8] = v;
    }
}

// ---------------- gather1: y1h = fp16( (sum_j x1h[col[j]]) * rsqrt(degI) + b1 ) ----------------
__global__ __launch_bounds__(256) void k_gather1(const f16* __restrict__ x1h,
                                                 const int* __restrict__ rowS,
                                                 const int* __restrict__ col,
                                                 const float* __restrict__ b1,
                                                 f16* __restrict__ y1h) {
    int node = blockIdx.x * 16 + (threadIdx.x >> 4);
    int f8 = threadIdx.x & 15;
    if (node >= NN) return;
    int s0 = rowS[node], s1 = rowS[node + 1];
    const uint4* x4 = (const uint4*)x1h;
    float acc[8] = {0.f, 0.f, 0.f, 0.f, 0.f, 0.f, 0.f, 0.f};
    int j = s0;
    for (; j + 3 < s1; j += 4) {
        int a0 = col[j], a1 = col[j + 1], a2 = col[j + 2], a3 = col[j + 3];
        uint4 v0 = x4[(size_t)a0 * 16 + f8];
        uint4 v1 = x4[(size_t)a1 * 16 + f8];
        uint4 v2 = x4[(size_t)a2 * 16 + f8];
        uint4 v3 = x4[(size_t)a3 * 16 + f8];
        const f16* h0 = (const f16*)&v0; const f16* h1 = (const f16*)&v1;
        const f16* h2 = (const f16*)&v2; const f16* h3 = (const f16*)&v3;
#pragma unroll
        for (int k = 0; k < 8; ++k)
            acc[k] += (float)h0[k] + (float)h1[k] + (float)h2[k] + (float)h3[k];
    }
    for (; j < s1; ++j) {
        int a = col[j];
        uint4 v = x4[(size_t)a * 16 + f8];
        const f16* hp = (const f16*)&v;
#pragma unroll
        for (int k = 0; k < 8; ++k) acc[k] += (float)hp[k];
    }
    float rs = rsqrtf(fmaxf((float)(s1 - s0), 1.f));
    const float4* b4 = (const float4*)b1;
    float4 ba = b4[f8 * 2], bb = b4[f8 * 2 + 1];
    f16x8 o;
    o[0] = (f16)(acc[0] * rs + ba.x); o[1] = (f16)(acc[1] * rs + ba.y);
    o[2] = (f16)(acc[2] * rs + ba.z); o[3] = (f16)(acc[3] * rs + ba.w);
    o[4] = (f16)(acc[4] * rs + bb.x); o[5] = (f16)(acc[5] * rs + bb.y);
    o[6] = (f16)(acc[6] * rs + bb.z); o[7] = (f16)(acc[7] * rs + bb.w);
    *(f16x8*)&y1h[(size_t)node * 128 + f8 * 8] = o;
}

// ---------------- BN stats ----------------
__global__ __launch_bounds__(256) void k_bnstats(const f16* __restrict__ y1h,
                                                 float* __restrict__ stats) {
    int f = threadIdx.x & 127;
    int ro = threadIdx.x >> 7;
    float s = 0.f, ss = 0.f;
    for (int i = blockIdx.x * 2 + ro; i < NN; i += gridDim.x * 2) {
        float v = (float)y1h[(size_t)i * 128 + f];
        s += v;
        ss += v * v;
    }
    atomicAdd(&stats[f], s);
    atomicAdd(&stats[128 + f], ss);
}

__global__ __launch_bounds__(128) void k_bnfinal(float* __restrict__ stats,
                                                 const float* __restrict__ gamma,
                                                 const float* __restrict__ beta) {
    int f = threadIdx.x;
    float mean = stats[f] * (1.f / NN);
    float var = stats[128 + f] * (1.f / NN) - mean * mean;
    var = fmaxf(var, 0.f);
    float sc = gamma[f] * rsqrtf(var + BN_EPS);
    stats[256 + f] = sc;
    stats[384 + f] = beta[f] - mean * sc;
}

// ---------------- GEMM2 (MFMA f16): x2h = (relu(BN(y1)) .* rsqrt(degO)) @ W2 ----------------
__global__ __launch_bounds__(256) void k_gemm2(const f16* __restrict__ y1h,
                                               const f16* __restrict__ W2t,
                                               const int* __restrict__ degO,
                                               const float* __restrict__ stats,
                                               f16* __restrict__ x2h) {
    __shared__ f16 Ah[128 * 128];
    __shared__ f16 Bt[64 * 128];
    __shared__ float sc[128], sh[128];
    int tid = threadIdx.x;
    int row0 = blockIdx.x * 128;
    if (tid < 128) { sc[tid] = stats[256 + tid]; sh[tid] = stats[384 + tid]; }
#pragma unroll
    for (int p = 0; p < 4; ++p) {
        int fi = p * 256 + tid;
        int r = fi >> 4, c = fi & 15;
        uint4 v = *(const uint4*)&W2t[fi * 8];
        *(uint4*)&Bt[r * 128 + ((c ^ (r & 7)) * 8)] = v;
    }
    __syncthreads();
#pragma unroll
    for (int p = 0; p < 8; ++p) {
        int fi = p * 256 + tid;
        int r = fi >> 4, c = fi & 15;
        int grow = row0 + r;
        f16x8 t;
        if (grow < NN) {
            uint4 v = *(const uint4*)&y1h[(size_t)grow * 128 + c * 8];
            const f16* hp = (const f16*)&v;
            float rs = rsqrtf(fmaxf((float)degO[grow], 1.f));
#pragma unroll
            for (int i = 0; i < 8; ++i) {
                int ch = c * 8 + i;
                float x = (float)hp[i] * sc[ch] + sh[ch];
                t[i] = (f16)(fmaxf(x, 0.f) * rs);
            }
        } else {
#pragma unroll
            for (int i = 0; i < 8; ++i) t[i] = (f16)0.f;
        }
        *(f16x8*)&Ah[r * 128 + ((c ^ (r & 7)) * 8)] = t;
    }
    __syncthreads();
    int l = tid & 63, w = tid >> 6;
    int lr = l & 15, g = l >> 4;
    int m0 = w * 32;
    f16x8 a[2][4];
#pragma unroll
    for (int m = 0; m < 2; ++m)
#pragma unroll
        for (int kk = 0; kk < 4; ++kk) {
            int row = m0 + m * 16 + lr;
            a[m][kk] = *(f16x8*)&Ah[row * 128 + (((kk * 4 + g) ^ (row & 7)) * 8)];
        }
    f32x4v acc[2][4];
#pragma unroll
    for (int m = 0; m < 2; ++m)
#pragma unroll
        for (int n = 0; n < 4; ++n) acc[m][n] = f32x4v{0.f, 0.f, 0.f, 0.f};
#pragma unroll
    for (int n = 0; n < 4; ++n) {
        int colr = n * 16 + lr;
        f16x8 b[4];
#pragma unroll
        for (int kk = 0; kk < 4; ++kk)
            b[kk] = *(f16x8*)&Bt[colr * 128 + (((kk * 4 + g) ^ (colr & 7)) * 8)];
#pragma unroll
        for (int m = 0; m < 2; ++m)
#pragma unroll
            for (int kk = 0; kk < 4; ++kk)
                acc[m][n] = __builtin_amdgcn_mfma_f32_16x16x32_f16(a[m][kk], b[kk], acc[m][n], 0, 0, 0);
    }
    __syncthreads();
#pragma unroll
    for (int m = 0; m < 2; ++m)
#pragma unroll
        for (int n = 0; n < 4; ++n)
#pragma unroll
            for (int q = 0; q < 4; ++q) {
                int row = m0 + m * 16 + g * 4 + q;
                Ah[row * 64 + n * 16 + lr] = (f16)acc[m][n][q];
            }
    __syncthreads();
#pragma unroll
    for (int p = 0; p < 4; ++p) {
        int idx = p * 64 + l;
        int r = idx >> 3, c = idx & 7;
        int row = m0 + r, grow = row0 + row;
        uint4 v = *(uint4*)&Ah[row * 64 + c * 8];
        if (grow < NN) *(uint4*)&x2h[(size_t)grow * 64 + c * 8] = v;
    }
}

// ---------------- gather2: out = (sum_j x2h[col[j]]) * rsqrt(degI) + b2 (fp32) ----------------
__global__ __launch_bounds__(256) void k_gather2(const f16* __restrict__ x2h,
                                                 const int* __restrict__ rowS,
                                                 const int* __restrict__ col,
                                                 const float* __restrict__ b2,
                                                 float* __restrict__ out) {
    int node = blockIdx.x * 32 + (threadIdx.x >> 3);
    int f8 = threadIdx.x & 7;
    if (node >= NN) return;
    int s0 = rowS[node], s1 = rowS[node + 1];
    const uint4* x4 = (const uint4*)x2h;
    float acc[8] = {0.f, 0.f, 0.f, 0.f, 0.f, 0.f, 0.f, 0.f};
    int j = s0;
    for (; j + 3 < s1; j += 4) {
        int a0 = col[j], a1 = col[j + 1], a2 = col[j + 2], a3 = col[j + 3];
        uint4 v0 = x4[(size_t)a0 * 8 + f8];
        uint4 v1 = x4[(size_t)a1 * 8 + f8];
        uint4 v2 = x4[(size_t)a2 * 8 + f8];
        uint4 v3 = x4[(size_t)a3 * 8 + f8];
        const f16* h0 = (const f16*)&v0; const f16* h1 = (const f16*)&v1;
        const f16* h2 = (const f16*)&v2; const f16* h3 = (const f16*)&v3;
#pragma unroll
        for (int k = 0; k < 8; ++k)
            acc[k] += (float)h0[k] + (float)h1[k] + (float)h2[k] + (float)h3[k];
    }
    for (; j < s1; ++j) {
        int a = col[j];
        uint4 v = x4[(size_t)a * 8 + f8];
        const f16* hp = (const f16*)&v;
#pragma unroll
        for (int k = 0; k < 8; ++k) acc[k] += (float)hp[k];
    }
    float rs = rsqrtf(fmaxf((float)(s1 - s0), 1.f));
    const float4* b4 = (const float4*)b2;
    float4 ba = b4[f8 * 2], bb = b4[f8 * 2 + 1];
    float4 o0, o1;
    o0.x = acc[0] * rs + ba.x; o0.y = acc[1] * rs + ba.y;
    o0.z = acc[2] * rs + ba.z; o0.w = acc[3] * rs + ba.w;
    o1.x = acc[4] * rs + bb.x; o1.y = acc[5] * rs + bb.y;
    o1.z = acc[6] * rs + bb.z; o1.w = acc[7] * rs + bb.w;
    *(float4*)&out[(size_t)node * 64 + f8 * 8] = o0;
    *(float4*)&out[(size_t)node * 64 + f8 * 8 + 4] = o1;
}

extern "C" void kernel_launch(void* const* d_in, const int* in_sizes, int n_in,
                              void* d_out, int out_size, void* d_ws, size_t ws_size,
                              hipStream_t stream) {
    const float* h     = (const float*)d_in[0];
    const float* W1    = (const float*)d_in[1];
    const float* b1    = (const float*)d_in[2];
    const float* W2    = (const float*)d_in[3];
    const float* b2    = (const float*)d_in[4];
    const float* gamma = (const float*)d_in[5];
    const float* beta  = (const float*)d_in[6];
    const int*   src   = (const int*)d_in[7];
    const int*   dst   = (const int*)d_in[8];
    float* out = (float*)d_out;

    // workspace layout (int units from base)
    int* base = (int*)d_ws;
    int* cntD = base;                       // 391
    int* cntS = base + NB;                  // 391
    float* stats = (float*)(base + 2 * NB); // 512 (zeroed with cnt arrays)
    int* baseD = base + 2 * NB + 512;       // 392
    int* baseS = baseD + (NB + 1);          // 392
    int* curD  = baseS + (NB + 1);          // 391
    int* curS  = curD + NB;                 // 391
    int* rowS  = curS + NB;                 // NN+1
    int* degO  = rowS + (NN + 1);           // NN
    int* col   = degO + NN;                 // NE
    size_t o = (size_t)(col + NE - base);
    o = (o + 3) & ~(size_t)3;               // 16B align
    uint2* pairs = (uint2*)(base + o);      // NE uint2
    o += (size_t)2 * NE;
    int* srcBuck = base + o;                // NE
    o += NE;
    o = (o + 3) & ~(size_t)3;
    f16* W1t = (f16*)(base + o);            // 16384 halves
    f16* W2t = W1t + 16384;                 // 8192 halves
    o += 8192 + 4096;
    f16* x1h = (f16*)(base + o);            // NN*128 halves
    o += (size_t)NN * 64;
    f16* y1h = (f16*)(base + o);            // NN*128 halves
    f16* x2h = x1h;                         // reuse (x1h dead after gather1)

    // zero: cntD, cntS, stats
    hipMemsetAsync(d_ws, 0, (size_t)(2 * NB + 512) * 4, stream);

    int bgrid = (NE + EPB - 1) / EPB;       // 196
    kA<<<bgrid, 256, 0, stream>>>(src, dst, cntD, cntS);
    kB<<<1, 512, 0, stream>>>(cntD, cntS, baseD, baseS, curD, curS, rowS);
    kC<<<bgrid, 256, 0, stream>>>(src, dst, curD, curS, pairs, srcBuck);
    kD<<<NB, 256, 0, stream>>>(pairs, baseD, rowS, col);
    kE<<<NB, 256, 0, stream>>>(srcBuck, baseS, degO);

    k_prep<<<96, 256, 0, stream>>>(W1, W2, W1t, W2t);

    int ggrid = (NN + 127) / 128;           // 782
    k_gemm1<<<ggrid, 256, 0, stream>>>(h, W1t, degO, x1h);
    k_gather1<<<(NN + 15) / 16, 256, 0, stream>>>(x1h, rowS, col, b1, y1h);
    k_bnstats<<<512, 256, 0, stream>>>(y1h, stats);
    k_bnfinal<<<1, 128, 0, stream>>>(stats, gamma, beta);
    k_gemm2<<<ggrid, 256, 0, stream>>>(y1h, W2t, degO, stats, x2h);
    k_gather2<<<(NN + 31) / 32, 256, 0, stream>>>(x2h, rowS, col, b2, out);
}

// Round 5
// 275.401 us; speedup vs baseline: 2.2152x; 1.1458x over previous
//
#include <hip/hip_runtime.h>

#define NN 100000
#define NE 1600000
#define NB 391          // (NN + 255) >> 8 buckets of 256 nodes
#define CAP 5120        // bucket capacity (mean 4096, ~16 sigma headroom)
#define EPB 4096        // edges per block in bucket pass
#define BN_EPS 1e-5f

typedef _Float16 f16;
typedef _Float16 f16x4 __attribute__((ext_vector_type(4)));
typedef _Float16 f16x8 __attribute__((ext_vector_type(8)));
typedef float f32x4v __attribute__((ext_vector_type(4)));

// ---------------- kInit: cursors + stats zero + fp16 transposed weights ----------------
__global__ __launch_bounds__(256) void kInit(const float* __restrict__ W1,
                                             const float* __restrict__ W2,
                                             f16* __restrict__ W1t,
                                             f16* __restrict__ W2t,
                                             int* __restrict__ curD,
                                             int* __restrict__ curS,
                                             float* __restrict__ stats) {
    int idx = blockIdx.x * 256 + threadIdx.x;
    if (idx < NB) { curD[idx] = idx * CAP; curS[idx] = idx * CAP; }
    if (idx < 512) stats[idx] = 0.f;
    if (idx < 16384) {
        int n = idx >> 7, k = idx & 127;
        W1t[idx] = (f16)W1[k * 128 + n];
    } else if (idx < 24576) {
        int j = idx - 16384;
        int n = j >> 7, k = j & 127;
        W2t[j] = (f16)W2[k * 64 + n];
    }
}

// ---------------- kC: bucketed scatter of edges (count -> reserve -> place) ----------------
__global__ __launch_bounds__(256) void kC(const int* __restrict__ src,
                                          const int* __restrict__ dst,
                                          int* __restrict__ curD,
                                          int* __restrict__ curS,
                                          unsigned* __restrict__ pairs,
                                          unsigned char* __restrict__ srcBuck) {
    __shared__ int hD[NB], hS[NB], bD_[NB], bS_[NB];
    for (int i = threadIdx.x; i < NB; i += 256) { hD[i] = 0; hS[i] = 0; }
    __syncthreads();
    int e0 = blockIdx.x * EPB;
    int e1 = min(e0 + EPB, NE);
    // pass 1: count
    for (int e = e0 + threadIdx.x; e < e1; e += 256) {
        atomicAdd(&hD[dst[e] >> 8], 1);
        atomicAdd(&hS[src[e] >> 8], 1);
    }
    __syncthreads();
    // reserve global ranges, reset local cursors
    for (int i = threadIdx.x; i < NB; i += 256) {
        bD_[i] = hD[i] ? atomicAdd(&curD[i], hD[i]) : 0;
        bS_[i] = hS[i] ? atomicAdd(&curS[i], hS[i]) : 0;
        hD[i] = 0; hS[i] = 0;
    }
    __syncthreads();
    // pass 2: place (packed records; defensive clamp vs capacity overflow)
    for (int e = e0 + threadIdx.x; e < e1; e += 256) {
        int d = dst[e], s = src[e];
        int db = d >> 8, sb = s >> 8;
        int rD = atomicAdd(&hD[db], 1);
        int posD = bD_[db] + rD;
        int limD = (db + 1) * CAP - 1;
        if (posD > limD) posD = limD;
        pairs[posD] = ((unsigned)s << 8) | (unsigned)(d & 255);
        int rS = atomicAdd(&hS[sb], 1);
        int posS = bS_[sb] + rS;
        int limS = (sb + 1) * CAP - 1;
        if (posS > limS) posS = limS;
        srcBuck[posS] = (unsigned char)(s & 255);
    }
}

// ---------------- kDE: blocks [0,NB): per-bucket CSR (rowS/rowE/col); [NB,2NB): degO ----------------
__global__ __launch_bounds__(256) void kDE(const unsigned* __restrict__ pairs,
                                           const unsigned char* __restrict__ srcBuck,
                                           const int* __restrict__ curD,
                                           const int* __restrict__ curS,
                                           int* __restrict__ rowS,
                                           int* __restrict__ rowE,
                                           int* __restrict__ col,
                                           int* __restrict__ degO) {
    __shared__ int cnt[256], s[256];
    int t = threadIdx.x;
    if (blockIdx.x < NB) {
        int b = blockIdx.x;
        int p0 = b * CAP, p1 = curD[b];
        cnt[t] = 0;
        __syncthreads();
        for (int p = p0 + t; p < p1; p += 256)
            atomicAdd(&cnt[pairs[p] & 255u], 1);
        __syncthreads();
        int v = cnt[t];
        s[t] = v;
        __syncthreads();
        for (int off = 1; off < 256; off <<= 1) {
            int x = (t >= off) ? s[t - off] : 0;
            __syncthreads();
            s[t] += x;
            __syncthreads();
        }
        int excl = s[t] - v;
        int node = b * 256 + t;
        if (node < NN) { rowS[node] = p0 + excl; rowE[node] = p0 + excl + v; }
        cnt[t] = excl;   // reuse as scatter cursor
        __syncthreads();
        for (int p = p0 + t; p < p1; p += 256) {
            unsigned e = pairs[p];
            int r = atomicAdd(&cnt[e & 255u], 1);
            col[p0 + r] = (int)(e >> 8);
        }
    } else {
        int b = blockIdx.x - NB;
        int p0 = b * CAP, p1 = curS[b];
        cnt[t] = 0;
        __syncthreads();
        for (int p = p0 + t; p < p1; p += 256)
            atomicAdd(&cnt[srcBuck[p]], 1);
        __syncthreads();
        int node = b * 256 + t;
        if (node < NN) degO[node] = cnt[t];
    }
}

// ---------------- GEMM1 (MFMA f16): x1h = (h .* rsqrt(degO)) @ W1 ----------------
__global__ __launch_bounds__(256) void k_gemm1(const float* __restrict__ h,
                                               const f16* __restrict__ W1t,
                                               const int* __restrict__ degO,
                                               f16* __restrict__ x1h) {
    __shared__ f16 Ah[128 * 128];
    __shared__ f16 Bt[128 * 128];
    int tid = threadIdx.x;
    int row0 = blockIdx.x * 128;
#pragma unroll
    for (int p = 0; p < 8; ++p) {
        int fi = p * 256 + tid;
        int r = fi >> 4, c = fi & 15;
        uint4 v = *(const uint4*)&W1t[fi * 8];
        *(uint4*)&Bt[r * 128 + ((c ^ (r & 7)) * 8)] = v;
    }
#pragma unroll
    for (int p = 0; p < 16; ++p) {
        int fi = p * 256 + tid;
        int r = fi >> 5, c4 = fi & 31;
        int grow = row0 + r;
        float4 av = float4{0.f, 0.f, 0.f, 0.f};
        float dv = 1.f;
        if (grow < NN) {
            av = *(const float4*)&h[(size_t)grow * 128 + c4 * 4];
            dv = (float)degO[grow];
        }
        float rs = rsqrtf(fmaxf(dv, 1.f));
        f16x4 t;
        t[0] = (f16)(av.x * rs); t[1] = (f16)(av.y * rs);
        t[2] = (f16)(av.z * rs); t[3] = (f16)(av.w * rs);
        int c8 = c4 >> 1, off = (c4 & 1) * 4;
        *(f16x4*)&Ah[r * 128 + ((c8 ^ (r & 7)) * 8) + off] = t;
    }
    __syncthreads();
    int l = tid & 63, w = tid >> 6;
    int lr = l & 15, g = l >> 4;
    int m0 = w * 32;
    f16x8 a[2][4];
#pragma unroll
    for (int m = 0; m < 2; ++m)
#pragma unroll
        for (int kk = 0; kk < 4; ++kk) {
            int row = m0 + m * 16 + lr;
            a[m][kk] = *(f16x8*)&Ah[row * 128 + (((kk * 4 + g) ^ (row & 7)) * 8)];
        }
    f32x4v acc[2][8];
#pragma unroll
    for (int m = 0; m < 2; ++m)
#pragma unroll
        for (int n = 0; n < 8; ++n) acc[m][n] = f32x4v{0.f, 0.f, 0.f, 0.f};
#pragma unroll
    for (int n = 0; n < 8; ++n) {
        int colr = n * 16 + lr;
        f16x8 b[4];
#pragma unroll
        for (int kk = 0; kk < 4; ++kk)
            b[kk] = *(f16x8*)&Bt[colr * 128 + (((kk * 4 + g) ^ (colr & 7)) * 8)];
#pragma unroll
        for (int m = 0; m < 2; ++m)
#pragma unroll
            for (int kk = 0; kk < 4; ++kk)
                acc[m][n] = __builtin_amdgcn_mfma_f32_16x16x32_f16(a[m][kk], b[kk], acc[m][n], 0, 0, 0);
    }
    __syncthreads();
#pragma unroll
    for (int m = 0; m < 2; ++m)
#pragma unroll
        for (int n = 0; n < 8; ++n)
#pragma unroll
            for (int q = 0; q < 4; ++q) {
                int row = m0 + m * 16 + g * 4 + q;
                Ah[row * 128 + n * 16 + lr] = (f16)acc[m][n][q];
            }
    __syncthreads();
#pragma unroll
    for (int p = 0; p < 8; ++p) {
        int idx = p * 64 + l;
        int r = idx >> 4, c = idx & 15;
        int row = m0 + r, grow = row0 + row;
        uint4 v = *(uint4*)&Ah[row * 128 + c * 8];
        if (grow < NN) *(uint4*)&x1h[(size_t)grow * 128 + c * 8] = v;
    }
}

// ---------------- gather1: y1h = fp16( (sum_j x1h[col[j]]) * rsqrt(degI) + b1 ) ----------------
__global__ __launch_bounds__(256) void k_gather1(const f16* __restrict__ x1h,
                                                 const int* __restrict__ rowS,
                                                 const int* __restrict__ rowE,
                                                 const int* __restrict__ col,
                                                 const float* __restrict__ b1,
                                                 f16* __restrict__ y1h) {
    int node = blockIdx.x * 16 + (threadIdx.x >> 4);
    int f8 = threadIdx.x & 15;
    if (node >= NN) return;
    int s0 = rowS[node], s1 = rowE[node];
    const uint4* x4 = (const uint4*)x1h;
    float acc[8] = {0.f, 0.f, 0.f, 0.f, 0.f, 0.f, 0.f, 0.f};
    int j = s0;
    for (; j + 7 < s1; j += 8) {
        uint4 v[8];
#pragma unroll
        for (int u = 0; u < 8; ++u)
            v[u] = x4[(size_t)col[j + u] * 16 + f8];
#pragma unroll
        for (int u = 0; u < 8; ++u) {
            const f16* hp = (const f16*)&v[u];
#pragma unroll
            for (int k = 0; k < 8; ++k) acc[k] += (float)hp[k];
        }
    }
    for (; j + 3 < s1; j += 4) {
        uint4 v[4];
#pragma unroll
        for (int u = 0; u < 4; ++u)
            v[u] = x4[(size_t)col[j + u] * 16 + f8];
#pragma unroll
        for (int u = 0; u < 4; ++u) {
            const f16* hp = (const f16*)&v[u];
#pragma unroll
            for (int k = 0; k < 8; ++k) acc[k] += (float)hp[k];
        }
    }
    for (; j < s1; ++j) {
        uint4 v = x4[(size_t)col[j] * 16 + f8];
        const f16* hp = (const f16*)&v;
#pragma unroll
        for (int k = 0; k < 8; ++k) acc[k] += (float)hp[k];
    }
    float rs = rsqrtf(fmaxf((float)(s1 - s0), 1.f));
    const float4* b4 = (const float4*)b1;
    float4 ba = b4[f8 * 2], bb = b4[f8 * 2 + 1];
    f16x8 o;
    o[0] = (f16)(acc[0] * rs + ba.x); o[1] = (f16)(acc[1] * rs + ba.y);
    o[2] = (f16)(acc[2] * rs + ba.z); o[3] = (f16)(acc[3] * rs + ba.w);
    o[4] = (f16)(acc[4] * rs + bb.x); o[5] = (f16)(acc[5] * rs + bb.y);
    o[6] = (f16)(acc[6] * rs + bb.z); o[7] = (f16)(acc[7] * rs + bb.w);
    *(f16x8*)&y1h[(size_t)node * 128 + f8 * 8] = o;
}

// ---------------- BN stats ----------------
__global__ __launch_bounds__(256) void k_bnstats(const f16* __restrict__ y1h,
                                                 float* __restrict__ stats) {
    int f = threadIdx.x & 127;
    int ro = threadIdx.x >> 7;
    float s = 0.f, ss = 0.f;
    for (int i = blockIdx.x * 2 + ro; i < NN; i += gridDim.x * 2) {
        float v = (float)y1h[(size_t)i * 128 + f];
        s += v;
        ss += v * v;
    }
    atomicAdd(&stats[f], s);
    atomicAdd(&stats[128 + f], ss);
}

__global__ __launch_bounds__(128) void k_bnfinal(float* __restrict__ stats,
                                                 const float* __restrict__ gamma,
                                                 const float* __restrict__ beta) {
    int f = threadIdx.x;
    float mean = stats[f] * (1.f / NN);
    float var = stats[128 + f] * (1.f / NN) - mean * mean;
    var = fmaxf(var, 0.f);
    float sc = gamma[f] * rsqrtf(var + BN_EPS);
    stats[256 + f] = sc;
    stats[384 + f] = beta[f] - mean * sc;
}

// ---------------- GEMM2 (MFMA f16): x2h = (relu(BN(y1)) .* rsqrt(degO)) @ W2 ----------------
__global__ __launch_bounds__(256) void k_gemm2(const f16* __restrict__ y1h,
                                               const f16* __restrict__ W2t,
                                               const int* __restrict__ degO,
                                               const float* __restrict__ stats,
                                               f16* __restrict__ x2h) {
    __shared__ f16 Ah[128 * 128];
    __shared__ f16 Bt[64 * 128];
    __shared__ float sc[128], sh[128];
    int tid = threadIdx.x;
    int row0 = blockIdx.x * 128;
    if (tid < 128) { sc[tid] = stats[256 + tid]; sh[tid] = stats[384 + tid]; }
#pragma unroll
    for (int p = 0; p < 4; ++p) {
        int fi = p * 256 + tid;
        int r = fi >> 4, c = fi & 15;
        uint4 v = *(const uint4*)&W2t[fi * 8];
        *(uint4*)&Bt[r * 128 + ((c ^ (r & 7)) * 8)] = v;
    }
    __syncthreads();
#pragma unroll
    for (int p = 0; p < 8; ++p) {
        int fi = p * 256 + tid;
        int r = fi >> 4, c = fi & 15;
        int grow = row0 + r;
        f16x8 t;
        if (grow < NN) {
            uint4 v = *(const uint4*)&y1h[(size_t)grow * 128 + c * 8];
            const f16* hp = (const f16*)&v;
            float rs = rsqrtf(fmaxf((float)degO[grow], 1.f));
#pragma unroll
            for (int i = 0; i < 8; ++i) {
                int ch = c * 8 + i;
                float x = (float)hp[i] * sc[ch] + sh[ch];
                t[i] = (f16)(fmaxf(x, 0.f) * rs);
            }
        } else {
#pragma unroll
            for (int i = 0; i < 8; ++i) t[i] = (f16)0.f;
        }
        *(f16x8*)&Ah[r * 128 + ((c ^ (r & 7)) * 8)] = t;
    }
    __syncthreads();
    int l = tid & 63, w = tid >> 6;
    int lr = l & 15, g = l >> 4;
    int m0 = w * 32;
    f16x8 a[2][4];
#pragma unroll
    for (int m = 0; m < 2; ++m)
#pragma unroll
        for (int kk = 0; kk < 4; ++kk) {
            int row = m0 + m * 16 + lr;
            a[m][kk] = *(f16x8*)&Ah[row * 128 + (((kk * 4 + g) ^ (row & 7)) * 8)];
        }
    f32x4v acc[2][4];
#pragma unroll
    for (int m = 0; m < 2; ++m)
#pragma unroll
        for (int n = 0; n < 4; ++n) acc[m][n] = f32x4v{0.f, 0.f, 0.f, 0.f};
#pragma unroll
    for (int n = 0; n < 4; ++n) {
        int colr = n * 16 + lr;
        f16x8 b[4];
#pragma unroll
        for (int kk = 0; kk < 4; ++kk)
            b[kk] = *(f16x8*)&Bt[colr * 128 + (((kk * 4 + g) ^ (colr & 7)) * 8)];
#pragma unroll
        for (int m = 0; m < 2; ++m)
#pragma unroll
            for (int kk = 0; kk < 4; ++kk)
                acc[m][n] = __builtin_amdgcn_mfma_f32_16x16x32_f16(a[m][kk], b[kk], acc[m][n], 0, 0, 0);
    }
    __syncthreads();
#pragma unroll
    for (int m = 0; m < 2; ++m)
#pragma unroll
        for (int n = 0; n < 4; ++n)
#pragma unroll
            for (int q = 0; q < 4; ++q) {
                int row = m0 + m * 16 + g * 4 + q;
                Ah[row * 64 + n * 16 + lr] = (f16)acc[m][n][q];
            }
    __syncthreads();
#pragma unroll
    for (int p = 0; p < 4; ++p) {
        int idx = p * 64 + l;
        int r = idx >> 3, c = idx & 7;
        int row = m0 + r, grow = row0 + row;
        uint4 v = *(uint4*)&Ah[row * 64 + c * 8];
        if (grow < NN) *(uint4*)&x2h[(size_t)grow * 64 + c * 8] = v;
    }
}

// ---------------- gather2: out = (sum_j x2h[col[j]]) * rsqrt(degI) + b2 (fp32) ----------------
__global__ __launch_bounds__(256) void k_gather2(const f16* __restrict__ x2h,
                                                 const int* __restrict__ rowS,
                                                 const int* __restrict__ rowE,
                                                 const int* __restrict__ col,
                                                 const float* __restrict__ b2,
                                                 float* __restrict__ out) {
    int node = blockIdx.x * 32 + (threadIdx.x >> 3);
    int f8 = threadIdx.x & 7;
    if (node >= NN) return;
    int s0 = rowS[node], s1 = rowE[node];
    const uint4* x4 = (const uint4*)x2h;
    float acc[8] = {0.f, 0.f, 0.f, 0.f, 0.f, 0.f, 0.f, 0.f};
    int j = s0;
    for (; j + 7 < s1; j += 8) {
        uint4 v[8];
#pragma unroll
        for (int u = 0; u < 8; ++u)
            v[u] = x4[(size_t)col[j + u] * 8 + f8];
#pragma unroll
        for (int u = 0; u < 8; ++u) {
            const f16* hp = (const f16*)&v[u];
#pragma unroll
            for (int k = 0; k < 8; ++k) acc[k] += (float)hp[k];
        }
    }
    for (; j + 3 < s1; j += 4) {
        uint4 v[4];
#pragma unroll
        for (int u = 0; u < 4; ++u)
            v[u] = x4[(size_t)col[j + u] * 8 + f8];
#pragma unroll
        for (int u = 0; u < 4; ++u) {
            const f16* hp = (const f16*)&v[u];
#pragma unroll
            for (int k = 0; k < 8; ++k) acc[k] += (float)hp[k];
        }
    }
    for (; j < s1; ++j) {
        uint4 v = x4[(size_t)col[j] * 8 + f8];
        const f16* hp = (const f16*)&v;
#pragma unroll
        for (int k = 0; k < 8; ++k) acc[k] += (float)hp[k];
    }
    float rs = rsqrtf(fmaxf((float)(s1 - s0), 1.f));
    const float4* b4 = (const float4*)b2;
    float4 ba = b4[f8 * 2], bb = b4[f8 * 2 + 1];
    float4 o0, o1;
    o0.x = acc[0] * rs + ba.x; o0.y = acc[1] * rs + ba.y;
    o0.z = acc[2] * rs + ba.z; o0.w = acc[3] * rs + ba.w;
    o1.x = acc[4] * rs + bb.x; o1.y = acc[5] * rs + bb.y;
    o1.z = acc[6] * rs + bb.z; o1.w = acc[7] * rs + bb.w;
    *(float4*)&out[(size_t)node * 64 + f8 * 8] = o0;
    *(float4*)&out[(size_t)node * 64 + f8 * 8 + 4] = o1;
}

extern "C" void kernel_launch(void* const* d_in, const int* in_sizes, int n_in,
                              void* d_out, int out_size, void* d_ws, size_t ws_size,
                              hipStream_t stream) {
    const float* h     = (const float*)d_in[0];
    const float* W1    = (const float*)d_in[1];
    const float* b1    = (const float*)d_in[2];
    const float* W2    = (const float*)d_in[3];
    const float* b2    = (const float*)d_in[4];
    const float* gamma = (const float*)d_in[5];
    const float* beta  = (const float*)d_in[6];
    const int*   src   = (const int*)d_in[7];
    const int*   dst   = (const int*)d_in[8];
    float* out = (float*)d_out;

    const size_t BSZ = (size_t)NB * CAP;    // 2,001,920 slots

    // workspace layout (int units from base)
    int* base = (int*)d_ws;
    float* stats = (float*)base;            // 512
    int* curD = base + 512;                 // NB
    int* curS = curD + NB;                  // NB
    int* rowS = curS + NB;                  // NN
    int* rowE = rowS + NN;                  // NN
    int* degO = rowE + NN;                  // NN
    int* col  = degO + NN;                  // BSZ ints
    unsigned* pairs = (unsigned*)(col + BSZ);   // BSZ u32
    unsigned char* srcBuck = (unsigned char*)(pairs + BSZ); // BSZ bytes
    size_t o = (size_t)(col + BSZ - base) + BSZ + (BSZ + 3) / 4;
    o = (o + 3) & ~(size_t)3;               // 16B align
    f16* W1t = (f16*)(base + o);            // 16384 halves
    f16* W2t = W1t + 16384;                 // 8192 halves
    o += 8192 + 4096;
    f16* x1h = (f16*)(base + o);            // NN*128 halves
    o += (size_t)NN * 64;
    f16* y1h = (f16*)(base + o);            // NN*128 halves
    f16* x2h = x1h;                         // reuse (x1h dead after gather1)

    kInit<<<97, 256, 0, stream>>>(W1, W2, W1t, W2t, curD, curS, stats);

    int bgrid = (NE + EPB - 1) / EPB;       // 391
    kC<<<bgrid, 256, 0, stream>>>(src, dst, curD, curS, pairs, srcBuck);
    kDE<<<2 * NB, 256, 0, stream>>>(pairs, srcBuck, curD, curS, rowS, rowE, col, degO);

    int ggrid = (NN + 127) / 128;           // 782
    k_gemm1<<<ggrid, 256, 0, stream>>>(h, W1t, degO, x1h);
    k_gather1<<<(NN + 15) / 16, 256, 0, stream>>>(x1h, rowS, rowE, col, b1, y1h);
    k_bnstats<<<512, 256, 0, stream>>>(y1h, stats);
    k_bnfinal<<<1, 128, 0, stream>>>(stats, gamma, beta);
    k_gemm2<<<ggrid, 256, 0, stream>>>(y1h, W2t, degO, stats, x2h);
    k_gather2<<<(NN + 31) / 32, 256, 0, stream>>>(x2h, rowS, rowE, col, b2, out);
}